// Round 5
// baseline (207.805 us; speedup 1.0000x reference)
//
#include <hip/hip_runtime.h>
#include <math.h>

// Hasegawa-Wakatani 2D RHS, 2048^2, all-spectral. Round 5:
//  - fused unpack + kx-IFFT + transposed store (S_i arrays eliminated,
//    saves 268 MB round-trip). Block owns rows (ky, 2048-ky); Hermitian
//    symmetry of n_hat/w_hat gives both rows of each packed spectrum from
//    one F-pair. Spectra stored pairwise interleaved: TTA=(T1,T2),
//    TTB=(T3,T4) as float4 -> 16B stores, 64B line = 4 consecutive ky
//    blocks (same XCD via chunk swizzle -> L2 write healing).
//  - bracket reads TTA/TTB rows contiguously; final re-reads TTB (L3-warm).
// 5 dispatches, ~540-570 MB HBM traffic.
//
// Pipeline:
//  pack_T     : n,w [x][y] --fftY, write^T--> W[ky][x]            (ws0)
//  unpack_invT: W row-pair --fftX, unpack, 4x ifftX--> TTA,TTB    (ws1..4)
//  bracket    : TTA/TTB rows --3x ifftKY, j, fftY--> BR [x][ky']  (ws0)
//  slabX      : BR cols --fftX, mask/N, ifftX, write^T--> ADVt    (ws1)
//  final      : ADVt,TTB rows --2x ifftKY, combine--> dn,dw       (d_out)

#define NF 2048
#define HALF 1024
#define K0F 0.15f
#define DEAL_LIM 682

typedef float2 cplx;

__device__ __forceinline__ int sw(int i){ return i ^ ((i>>4)&15) ^ ((i>>8)&15); }
__device__ __forceinline__ cplx cmul(cplx a, cplx b){ return make_float2(a.x*b.x - a.y*b.y, a.x*b.y + a.y*b.x); }
__device__ __forceinline__ cplx cadd(cplx a, cplx b){ return make_float2(a.x+b.x, a.y+b.y); }
__device__ __forceinline__ cplx csub(cplx a, cplx b){ return make_float2(a.x-b.x, a.y-b.y); }
template<int SIGN> __device__ __forceinline__ cplx rot90(cplx z){
  return (SIGN>0)? make_float2(-z.y,z.x) : make_float2(z.y,-z.x); }
__device__ __forceinline__ void lput(cplx* L, int i, cplx v){ L[sw(i)] = v; }
__device__ __forceinline__ cplx lget(const cplx* L, int i){ return L[sw(i)]; }

// chunked XCD swizzle (grid % 8 == 0): consecutive logical blocks -> same XCD
__device__ __forceinline__ int xcd_chunk(int bid, int nwg){
  return (bid & 7) * (nwg >> 3) + (bid >> 3);
}

// ---- in-place radix-8 stage: read all, barrier, write all, barrier.
template<int SIGN, int TPR, int M>
__device__ __forceinline__ void stage8_ip(cplx* X, int t) {
  constexpr int BPT = 256 / TPR;
  const float ang = (float)SIGN * 0.0030679615757712824f; // 2*pi/2048
  cplx a[BPT][8];
#pragma unroll
  for (int u = 0; u < BPT; ++u) {
    const int b = t + u * TPR;
#pragma unroll
    for (int k = 0; k < 8; ++k) a[u][k] = X[sw(b + 256 * k)];
  }
  __syncthreads();
#pragma unroll
  for (int u = 0; u < BPT; ++u) {
    const int b = t + u * TPR;
    const int i = b & (M - 1);
    const int jm = b - i;
    cplx a0=a[u][0], a1=a[u][1], a2=a[u][2], a3=a[u][3],
         a4=a[u][4], a5=a[u][5], a6=a[u][6], a7=a[u][7];
    cplx t0=cadd(a0,a4), t1=csub(a0,a4), t2=cadd(a2,a6), t3=rot90<SIGN>(csub(a2,a6));
    cplx E0=cadd(t0,t2), E2=csub(t0,t2), E1=cadd(t1,t3), E3=csub(t1,t3);
    cplx u0=cadd(a1,a5), u1=csub(a1,a5), u2=cadd(a3,a7), u3=rot90<SIGN>(csub(a3,a7));
    cplx O0=cadd(u0,u2), O2=csub(u0,u2), O1=cadd(u1,u3), O3=csub(u1,u3);
    const float hh = 0.70710678118654752440f;
    O1 = cmul(O1, make_float2(hh, (float)SIGN*hh));
    O2 = rot90<SIGN>(O2);
    O3 = cmul(O3, make_float2(-hh, (float)SIGN*hh));
    cplx y0=cadd(E0,O0), y4=csub(E0,O0);
    cplx y1=cadd(E1,O1), y5=csub(E1,O1);
    cplx y2=cadd(E2,O2), y6=csub(E2,O2);
    cplx y3=cadd(E3,O3), y7=csub(E3,O3);
    float sn, cs;
    __sincosf(ang * (float)jm, &sn, &cs);
    cplx w1 = make_float2(cs, sn);
    cplx w2 = cmul(w1,w1), w3 = cmul(w2,w1), w4 = cmul(w2,w2);
    cplx w5 = cmul(w3,w2), w6 = cmul(w3,w3), w7 = cmul(w4,w3);
    const int o = 8*jm + i;
    X[sw(o)]       = y0;
    X[sw(o+M)]     = cmul(y1,w1);
    X[sw(o+2*M)]   = cmul(y2,w2);
    X[sw(o+3*M)]   = cmul(y3,w3);
    X[sw(o+4*M)]   = cmul(y4,w4);
    X[sw(o+5*M)]   = cmul(y5,w5);
    X[sw(o+6*M)]   = cmul(y6,w6);
    X[sw(o+7*M)]   = cmul(y7,w7);
  }
  __syncthreads();
}

template<int SIGN, int TPR>
__device__ __forceinline__ void stage4_ip(cplx* X, int t){
  constexpr int QPT = 512 / TPR;
  cplx a[QPT][4];
#pragma unroll
  for (int u=0; u<QPT; ++u){
    const int b = t + u*TPR;
#pragma unroll
    for (int k=0;k<4;++k) a[u][k] = X[sw(b + 512*k)];
  }
  __syncthreads();
#pragma unroll
  for (int u=0; u<QPT; ++u){
    const int b = t + u*TPR;
    cplx a0=a[u][0], a1=a[u][1], a2=a[u][2], a3=a[u][3];
    cplx t0=cadd(a0,a2), t1=csub(a0,a2), t2=cadd(a1,a3), t3=rot90<SIGN>(csub(a1,a3));
    X[sw(b)]       = cadd(t0,t2);
    X[sw(b+512)]   = cadd(t1,t3);
    X[sw(b+1024)]  = csub(t0,t2);
    X[sw(b+1536)]  = csub(t1,t3);
  }
  __syncthreads();
}

// entry barrier covers caller's LDS fill; exits with results published.
template<int SIGN, int TPR>
__device__ __forceinline__ void fft_ip(cplx* X, int t){
  __syncthreads();
  stage8_ip<SIGN,TPR,1>(X,t);
  stage8_ip<SIGN,TPR,8>(X,t);
  stage8_ip<SIGN,TPR,64>(X,t);
  stage4_ip<SIGN,TPR>(X,t);
}

// ---- spectral unpack: one of the 4 packed spectra at one (kx,ky) point.
// a = F(ky,kx), b = F(-ky,-kx); nh/wh via Hermitian split of fft2(n + i*w).
template<int I>
__device__ __forceinline__ cplx unpack_one(cplx a, cplx b,
    float kxv, float kyv, float kxp, float kyp) {
  cplx nh = make_float2(0.5f*(a.x + b.x),  0.5f*(a.y - b.y));
  cplx wh = make_float2(0.5f*(a.y + b.y), -0.5f*(a.x - b.x));
  float k2 = kxv*kxv + kyv*kyv;
  if constexpr (I == 0) {
    float pinv = (k2 > 1e-12f) ? (-1.0f/k2) : 0.0f;
    cplx ph = make_float2(wh.x*pinv, wh.y*pinv);
    return make_float2(-kxp*ph.y - kyp*ph.x, kxp*ph.x - kyp*ph.y);
  } else if constexpr (I == 1) {
    return make_float2(-kxp*nh.y - kyp*nh.x, kxp*nh.x - kyp*nh.y);
  } else if constexpr (I == 2) {
    return make_float2(-kxp*wh.y - kyp*wh.x, kxp*wh.x - kyp*wh.y);
  } else {
    float pinv = (k2 > 1e-12f) ? (-1.0f/k2) : 0.0f;
    cplx ph = make_float2(wh.x*pinv, wh.y*pinv);
    float dnc = 0.001f * k2;
    cplx Ln = make_float2( kyp*ph.y + (ph.x - nh.x) - dnc*nh.x,
                          -kyp*ph.x + (ph.y - nh.y) - dnc*nh.y);
    cplx Lw = make_float2( kyp*nh.y + (ph.x - nh.x) - dnc*wh.x,
                          -kyp*nh.x + (ph.y - nh.y) - dnc*wh.y);
    return make_float2(Ln.x - Lw.y, Ln.y + Lw.x);
  }
}

template<int I>
__device__ __forceinline__ void build_spec(cplx* Wm, const cplx* Fm, const cplx* Fp,
                                           int t, float kyv, float kyp) {
#pragma unroll
  for (int u=0; u<8; ++u){
    int kx = t + u*256;
    int kx2 = (NF - kx) & (NF - 1);
    int sx = (kx < HALF) ? kx : kx - NF;
    float kxv = K0F * (float)sx;
    float kxp = (kx == HALF) ? 0.0f : kxv;
    lput(Wm, kx, unpack_one<I>(lget(Fm, kx), lget(Fp, kx2), kxv, kyv, kxp, kyp));
  }
}

// ---- kernels -------------------------------------------------------------

// 4 x-rows: load n,w, fft along y, transposed store -> out[ky][x]
__global__ void __launch_bounds__(512) k_fwd_pack_T(const float* __restrict__ nIn,
                                                    const float* __restrict__ wIn,
                                                    cplx* __restrict__ out) {
  __shared__ cplx L[4*NF];
  const int tid = threadIdx.x;
  const int lb = xcd_chunk(blockIdx.x, gridDim.x);
  const int xb = lb*4;
#pragma unroll
  for (int u=0; u<4; ++u){
    int f = tid + u*512;           // 0..2047
    int r = f >> 9;                // row 0..3
    int p = f & 511;               // float4 idx
    float4 nv = ((const float4*)(nIn + (size_t)(xb+r)*NF))[p];
    float4 wv = ((const float4*)(wIn + (size_t)(xb+r)*NF))[p];
    cplx* Lr = L + r*NF;
    lput(Lr, 4*p+0, make_float2(nv.x, wv.x));
    lput(Lr, 4*p+1, make_float2(nv.y, wv.y));
    lput(Lr, 4*p+2, make_float2(nv.z, wv.z));
    lput(Lr, 4*p+3, make_float2(nv.w, wv.w));
  }
  const int row = tid >> 7, t = tid & 127;
  fft_ip<-1,128>(L + row*NF, t);
  float4* o4 = (float4*)out;
#pragma unroll
  for (int u=0; u<8; ++u){
    int f = tid + u*512;           // 0..4095
    int ky = f >> 1;
    int xp = f & 1;                // local x-pair
    cplx a = lget(L + (2*xp)*NF, ky);
    cplx b = lget(L + (2*xp+1)*NF, ky);
    o4[(size_t)ky*(NF/2) + lb*2 + xp] = make_float4(a.x,a.y,b.x,b.y);
  }
}

// row-pair (ky, NF-ky): fftX both, unpack all 4 spectra, ifftX each,
// store interleaved-transposed: TTA[x][ky]=(T1,T2), TTB[x][ky]=(T3,T4).
__global__ void __launch_bounds__(512) k_unpack_invT(const cplx* __restrict__ in,
                                                     float4* __restrict__ TTA,
                                                     float4* __restrict__ TTB) {
  __shared__ cplx F0[NF], F1[NF], W0[NF], W1[NF];
  const int tid = threadIdx.x;
  const int b = xcd_chunk(blockIdx.x, gridDim.x);   // 0..1023
  const int kyA = b;
  const int kyB = (b == 0) ? HALF : NF - b;
  const int half = tid >> 8;
  const int t = tid & 255;
  cplx* Fm = half ? F1 : F0;
  {
    const cplx* g = in + (size_t)(half ? kyB : kyA)*NF;
#pragma unroll
    for (int u=0; u<4; ++u){
      int p = t + u*256;
      float4 v = ((const float4*)g)[p];
      lput(Fm, 2*p,   make_float2(v.x,v.y));
      lput(Fm, 2*p+1, make_float2(v.z,v.w));
    }
    fft_ip<-1,256>(Fm, t);
  }
  // conj-mirror partner row: for b=0 each row is self-paired
  const cplx* Fp = (b == 0) ? (const cplx*)Fm : (half ? F0 : F1);
  cplx* Wm = half ? W1 : W0;
  const int kyM = half ? kyB : kyA;
  const int sy = (kyM < HALF) ? kyM : kyM - NF;
  const float kyv = K0F * (float)sy;
  const float kyp = (kyM == HALF) ? 0.0f : kyv;
  const float sc = 1.0f/(float)NF;
  cplx r[8];

  // S1 -> regs
  build_spec<0>(Wm, Fm, Fp, t, kyv, kyp);
  fft_ip<1,256>(Wm, t);
#pragma unroll
  for (int u=0; u<8; ++u) r[u] = lget(Wm, t + u*256);
  // S2 -> store (T1,T2)
  build_spec<1>(Wm, Fm, Fp, t, kyv, kyp);
  fft_ip<1,256>(Wm, t);
#pragma unroll
  for (int u=0; u<8; ++u){
    int x = t + u*256;
    cplx z = lget(Wm, x);
    TTA[(size_t)x*NF + kyM] = make_float4(sc*r[u].x, sc*r[u].y, sc*z.x, sc*z.y);
  }
  // S3 -> regs
  build_spec<2>(Wm, Fm, Fp, t, kyv, kyp);
  fft_ip<1,256>(Wm, t);
#pragma unroll
  for (int u=0; u<8; ++u) r[u] = lget(Wm, t + u*256);
  // S4 -> store (T3,T4)
  build_spec<3>(Wm, Fm, Fp, t, kyv, kyp);
  fft_ip<1,256>(Wm, t);
#pragma unroll
  for (int u=0; u<8; ++u){
    int x = t + u*256;
    cplx z = lget(Wm, x);
    TTB[(size_t)x*NF + kyM] = make_float4(sc*r[u].x, sc*r[u].y, sc*z.x, sc*z.y);
  }
}

// 1 x-row: ifft T1 (dphi->regs), ifft T2 (jn), ifft T3 (jw), fwd fft j -> BR
__global__ void __launch_bounds__(256) k_bracket(const float4* __restrict__ TTA,
                                                 const float4* __restrict__ TTB,
                                                 cplx* __restrict__ out) {
  __shared__ cplx A[NF], S[NF];
  const int t = threadIdx.x;
  const size_t base = (size_t)blockIdx.x * NF;
#pragma unroll
  for (int u=0; u<8; ++u){
    int p = t + u*256;
    float4 v = TTA[base + p];
    lput(A, p, make_float2(v.x, v.y));   // T1 = dphi pair
    lput(S, p, make_float2(v.z, v.w));   // T2 = dn pair
  }
  fft_ip<1,256>(A, t);                   // (dphix,dphiy)*N
  cplx dphi[8];
#pragma unroll
  for (int u=0; u<8; ++u) dphi[u] = lget(A, t + u*256);
  fft_ip<1,256>(S, t);                   // (dnx,dny)*N
  float jn[8];
#pragma unroll
  for (int u=0; u<8; ++u){
    cplx dd = lget(S, t + u*256);
    jn[u] = dphi[u].x*dd.y - dphi[u].y*dd.x;
  }
#pragma unroll
  for (int u=0; u<8; ++u){
    int p = t + u*256;
    float4 v = TTB[base + p];
    lput(A, p, make_float2(v.x, v.y));   // T3 = dw pair (T4 half dropped)
  }
  fft_ip<1,256>(A, t);                   // (dwx,dwy)*N
  const float sc2 = 1.0f/((float)NF*(float)NF);
#pragma unroll
  for (int u=0; u<8; ++u){
    int c = t + u*256;
    cplx dd = lget(A, c);
    float jw = dphi[u].x*dd.y - dphi[u].y*dd.x;
    lput(S, c, make_float2(sc2*jn[u], sc2*jw));   // own-slot r/w
  }
  fft_ip<-1,256>(S, t);                  // fft(j_n + i*j_w) along y
  float4* o4 = (float4*)(out + base);
#pragma unroll
  for (int u=0; u<4; ++u){
    int p = t + u*256;
    cplx a = lget(S, 2*p), b = lget(S, 2*p+1);
    o4[p] = make_float4(a.x,a.y,b.x,b.y);
  }
}

// 4 ky'-columns: fftX, 2/3 mask * (1/N), ifftX, transposed write [x][ky']
__global__ void __launch_bounds__(512) k_slabX(const cplx* __restrict__ in,
                                               cplx* __restrict__ out) {
  __shared__ cplx L[4*NF];
  const int tid = threadIdx.x;
  const int lb = xcd_chunk(blockIdx.x, gridDim.x);
  const int cb = lb*4;
#pragma unroll
  for (int u=0; u<8; ++u){
    int f = tid + u*512;           // 0..4095
    int x = f >> 1, j = f & 1;
    float4 v = ((const float4*)(in + (size_t)x*NF + cb))[j];
    lput(L + (2*j)*NF,   x, make_float2(v.x,v.y));
    lput(L + (2*j+1)*NF, x, make_float2(v.z,v.w));
  }
  const int row = tid >> 7, t = tid & 127;
  fft_ip<-1,128>(L + row*NF, t);
  const float sc = 1.0f/(float)NF;
#pragma unroll
  for (int v2=0; v2<16; ++v2){
    int g = tid + v2*512;          // 0..8191
    int c = g >> 11, kk = g & 2047;
    int ky = cb + c;
    int sy = (ky < HALF) ? ky : ky - NF;
    int sx = (kk < HALF) ? kk : kk - NF;
    float m = (((sy<0?-sy:sy) <= DEAL_LIM) && ((sx<0?-sx:sx) <= DEAL_LIM)) ? sc : 0.0f;
    cplx z = lget(L + c*NF, kk);
    lput(L + c*NF, kk, make_float2(m*z.x, m*z.y));   // own-slot r/w
  }
  fft_ip<1,128>(L + row*NF, t);
#pragma unroll
  for (int u=0; u<8; ++u){
    int f = tid + u*512;
    int x = f >> 1, j = f & 1;
    cplx a = lget(L + (2*j)*NF, x);
    cplx b = lget(L + (2*j+1)*NF, x);
    ((float4*)(out + (size_t)x*NF + cb))[j] = make_float4(a.x,a.y,b.x,b.y);
  }
}

// 1 x-row: ifft ADVt, ifft T4 (from TTB, L3-warm), combine -> dn,dw
__global__ void __launch_bounds__(256) k_final(const cplx* __restrict__ ADVt,
                                               const float4* __restrict__ TTB,
                                               float* __restrict__ outF) {
  __shared__ cplx A[NF], S[NF];
  const int t = threadIdx.x;
  const size_t base = (size_t)blockIdx.x * NF;
#pragma unroll
  for (int u=0; u<4; ++u){
    int p = t + u*256;
    float4 v = ((const float4*)(ADVt + base))[p];
    lput(A, 2*p,   make_float2(v.x,v.y));
    lput(A, 2*p+1, make_float2(v.z,v.w));
  }
#pragma unroll
  for (int u=0; u<8; ++u){
    int p = t + u*256;
    float4 v = TTB[base + p];
    lput(S, p, make_float2(v.z, v.w));   // T4 = (Ln,Lw)
  }
  fft_ip<1,256>(A, t);                   // adv*N
  cplx adv[8];
#pragma unroll
  for (int u=0; u<8; ++u) adv[u] = lget(A, t + u*256);
  fft_ip<1,256>(S, t);                   // (Ln,Lw)*N
  const float sc = 1.0f/(float)NF;
  const size_t NSQ = (size_t)NF*NF;
#pragma unroll
  for (int u=0; u<8; ++u){
    int c = t + u*256;
    cplx Lv = lget(S, c);
    outF[base + c]       = sc*(Lv.x - adv[u].x);   // dn
    outF[NSQ + base + c] = sc*(Lv.y - adv[u].y);   // dw
  }
}

extern "C" void kernel_launch(void* const* d_in, const int* in_sizes, int n_in,
                              void* d_out, int out_size, void* d_ws, size_t ws_size,
                              hipStream_t stream) {
  const float* nIn = (const float*)d_in[0];
  const float* wIn = (const float*)d_in[1];
  float* outF = (float*)d_out;

  const size_t B = (size_t)NF * NF * sizeof(cplx);   // 33.5 MB
  char* ws = (char*)d_ws;
  cplx*   ws0  = (cplx*)(ws);              // W, later BR
  float4* TTA  = (float4*)(ws + 1*B);      // (T1,T2) interleaved, 2 buffers
  float4* TTB  = (float4*)(ws + 3*B);      // (T3,T4) interleaved, 2 buffers
  cplx*   ADVt = (cplx*)(ws + 1*B);        // reuses TTA space after bracket

  // forward pass 1 (along y) with transposed store
  k_fwd_pack_T <<<512, 512, 0, stream>>>(nIn, wIn, ws0);        // W[ky][x]

  // forward pass 2 + unpack + inverse pass 1 + transposed store, fused
  k_unpack_invT <<<1024, 512, 0, stream>>>(ws0, TTA, TTB);

  // bracket (finishes ifftY) + fwd fftY -> BR [x][ky']
  k_bracket <<<NF, 256, 0, stream>>>(TTA, TTB, ws0);

  // fftX + dealias + ifftX fused, transposed write -> ADVt [x][ky']
  k_slabX <<<512, 512, 0, stream>>>(ws0, ADVt);

  // final: ifftY of ADVt & T4, combine -> d_out
  k_final <<<NF, 256, 0, stream>>>(ADVt, TTB, outF);
}